// Round 1
// baseline (1798.486 us; speedup 1.0000x reference)
//
#include <hip/hip_runtime.h>

#define SS   2048
#define DD   2560
#define HH   32
#define DHH  80
#define DPAD 96
#define NII  10240
#define NTOK 4096

typedef __attribute__((ext_vector_type(8))) __bf16 bf16x8;
typedef __attribute__((ext_vector_type(4))) float  f32x4;

__device__ __forceinline__ float bf2f(unsigned short h) {
  union { unsigned u; float f; } c; c.u = ((unsigned)h) << 16; return c.f;
}
__device__ __forceinline__ unsigned short f2bf(float f) {
  union { float f; unsigned u; } c; c.f = f;
  unsigned r = c.u + 0x7FFFu + ((c.u >> 16) & 1u);
  return (unsigned short)(r >> 16);
}

__device__ __forceinline__ void gl_lds16(const void* gptr, void* lptr) {
  __builtin_amdgcn_global_load_lds((__attribute__((address_space(1))) void*)gptr,
                                   (__attribute__((address_space(3))) void*)lptr,
                                   16, 0, 0);
}

// ---------------- weight transpose: W[K][N] fp32 -> Wt[N][K] bf16 ----------------
__global__ __launch_bounds__(256) void wt_transpose(const float* __restrict__ W,
                                                    unsigned short* __restrict__ Wt,
                                                    int K, int N) {
  __shared__ float tile[32][33];
  const int tx = threadIdx.x & 31, ty = threadIdx.x >> 5;
  const int n0 = blockIdx.x * 32, k0 = blockIdx.y * 32;
#pragma unroll
  for (int i = 0; i < 32; i += 8)
    tile[ty + i][tx] = W[(size_t)(k0 + ty + i) * N + n0 + tx];
  __syncthreads();
#pragma unroll
  for (int i = 0; i < 32; i += 8)
    Wt[(size_t)(n0 + ty + i) * K + k0 + tx] = f2bf(tile[tx][ty + i]);
}

// ---------------- LayerNorm: fp32 in -> bf16 out ----------------
__global__ __launch_bounds__(256) void ln_kernel(const float* __restrict__ X,
                                                 const float* __restrict__ G,
                                                 const float* __restrict__ Bb,
                                                 unsigned short* __restrict__ Xo) {
  const int row = blockIdx.x;
  const float4* xr = (const float4*)(X + (size_t)row * DD);
  float s = 0.f, ss = 0.f;
  for (int i = threadIdx.x; i < DD / 4; i += 256) {
    float4 v = xr[i];
    s  += v.x + v.y + v.z + v.w;
    ss += v.x * v.x + v.y * v.y + v.z * v.z + v.w * v.w;
  }
#pragma unroll
  for (int o = 32; o > 0; o >>= 1) { s += __shfl_down(s, o, 64); ss += __shfl_down(ss, o, 64); }
  __shared__ float red[8];
  const int w = threadIdx.x >> 6;
  if ((threadIdx.x & 63) == 0) { red[w] = s; red[4 + w] = ss; }
  __syncthreads();
  if (threadIdx.x == 0) {
    float ts  = red[0] + red[1] + red[2] + red[3];
    float tss = red[4] + red[5] + red[6] + red[7];
    float mu  = ts * (1.f / DD);
    float var = tss * (1.f / DD) - mu * mu;
    red[0] = mu; red[1] = rsqrtf(var + 1e-5f);
  }
  __syncthreads();
  const float mu = red[0], rstd = red[1];
  const float4* gr = (const float4*)G;
  const float4* br = (const float4*)Bb;
  for (int i = threadIdx.x; i < DD / 4; i += 256) {
    float4 v = xr[i], g = gr[i], b = br[i];
    ushort4 o;
    o.x = f2bf((v.x - mu) * rstd * g.x + b.x);
    o.y = f2bf((v.y - mu) * rstd * g.y + b.y);
    o.z = f2bf((v.z - mu) * rstd * g.z + b.z);
    o.w = f2bf((v.w - mu) * rstd * g.w + b.w);
    *(ushort4*)&Xo[(size_t)row * DD + i * 4] = o;
  }
}

// ---------------- RoPE + head-layout: qkv[4096][7680] -> Qp/Kp [B,H,S,96], Vt [B,H,80,S] ----------------
__global__ __launch_bounds__(256) void rope_kernel(const unsigned short* __restrict__ qkv,
                                                   unsigned short* __restrict__ Qp,
                                                   unsigned short* __restrict__ Kp,
                                                   unsigned short* __restrict__ Vt) {
  const int tok = blockIdx.x;
  const int b = tok / SS, s = tok % SS;
  __shared__ float cs[16], sn[16];
  if (threadIdx.x < 16) {
    float inv = powf(10000.f, -(float)threadIdx.x / 16.f);
    float ang = (float)s * inv;
    cs[threadIdx.x] = cosf(ang);
    sn[threadIdx.x] = sinf(ang);
  }
  __syncthreads();
  const unsigned short* row = qkv + (size_t)tok * (3 * DD);
  for (int idx = threadIdx.x; idx < 2 * HH * DPAD; idx += 256) {
    const int which = idx / (HH * DPAD);
    const int rrem  = idx % (HH * DPAD);
    const int h = rrem / DPAD, d = rrem % DPAD;
    float val = 0.f;
    if (d < DHH) {
      const unsigned short* base = row + which * DD + h * DHH;
      if (d < 16) {
        float x1 = bf2f(base[d]), x2 = bf2f(base[d + 16]);
        val = x1 * cs[d] - x2 * sn[d];
      } else if (d < 32) {
        int i2 = d - 16;
        float x1 = bf2f(base[i2]), x2 = bf2f(base[d]);
        val = x2 * cs[i2] + x1 * sn[i2];
      } else {
        val = bf2f(base[d]);
      }
    }
    unsigned short* outp = which ? Kp : Qp;
    outp[(((size_t)b * HH + h) * SS + s) * DPAD + d] = f2bf(val);
  }
  for (int idx = threadIdx.x; idx < DD; idx += 256) {
    const int h = idx / DHH, d = idx % DHH;
    Vt[(((size_t)b * HH + h) * DHH + d) * SS + s] = row[2 * DD + idx];
  }
}

// ---------------- flash attention (causal), per-wave 16 q-rows ----------------
__global__ __launch_bounds__(256) void attn_kernel(const unsigned short* __restrict__ Qp,
                                                   const unsigned short* __restrict__ Kp,
                                                   const unsigned short* __restrict__ Vt,
                                                   unsigned short* __restrict__ O) {
  const int qblk = blockIdx.x, bh = blockIdx.y;
  const int w = threadIdx.x >> 6, lane = threadIdx.x & 63;
  const int lr = lane & 15, lg = lane >> 4;
  const int q0 = qblk * 64 + w * 16;
  const unsigned short* Qh = Qp + (size_t)bh * SS * DPAD;
  const unsigned short* Kh = Kp + (size_t)bh * SS * DPAD;
  const unsigned short* Vh = Vt + (size_t)bh * DHH * SS;
  __shared__ __align__(16) unsigned short Plds[4][16][32];

  bf16x8 qf[3];
#pragma unroll
  for (int c = 0; c < 3; ++c)
    qf[c] = *(const bf16x8*)&Qh[(size_t)(q0 + lr) * DPAD + c * 32 + lg * 8];

  f32x4 oacc[5];
#pragma unroll
  for (int d = 0; d < 5; ++d) oacc[d] = (f32x4){0.f, 0.f, 0.f, 0.f};
  float mrow[4], lrow[4];
#pragma unroll
  for (int r = 0; r < 4; ++r) { mrow[r] = -1e30f; lrow[r] = 0.f; }

  const float scl = 0.11180339887498949f;  // 80^-0.5
  const int nt = (q0 + 15) / 32 + 1;
  for (int t = 0; t < nt; ++t) {
    const int kv0 = t * 32;
    f32x4 s0 = (f32x4){0.f, 0.f, 0.f, 0.f};
    f32x4 s1 = (f32x4){0.f, 0.f, 0.f, 0.f};
#pragma unroll
    for (int c = 0; c < 3; ++c) {
      bf16x8 kf0 = *(const bf16x8*)&Kh[(size_t)(kv0 + lr) * DPAD + c * 32 + lg * 8];
      bf16x8 kf1 = *(const bf16x8*)&Kh[(size_t)(kv0 + 16 + lr) * DPAD + c * 32 + lg * 8];
      s0 = __builtin_amdgcn_mfma_f32_16x16x32_bf16(qf[c], kf0, s0, 0, 0, 0);
      s1 = __builtin_amdgcn_mfma_f32_16x16x32_bf16(qf[c], kf1, s1, 0, 0, 0);
    }
#pragma unroll
    for (int r = 0; r < 4; ++r) {
      const int qr = q0 + lg * 4 + r;
      float v0 = (kv0 + lr > qr)      ? -1e30f : s0[r] * scl;
      float v1 = (kv0 + 16 + lr > qr) ? -1e30f : s1[r] * scl;
      float mx = fmaxf(v0, v1);
#pragma unroll
      for (int mk = 1; mk < 16; mk <<= 1) mx = fmaxf(mx, __shfl_xor(mx, mk, 64));
      const float mnew = fmaxf(mrow[r], mx);
      const float resc = __expf(mrow[r] - mnew);
      const float p0 = __expf(v0 - mnew);
      const float p1 = __expf(v1 - mnew);
      float rs = p0 + p1;
#pragma unroll
      for (int mk = 1; mk < 16; mk <<= 1) rs += __shfl_xor(rs, mk, 64);
      lrow[r] = lrow[r] * resc + rs;
      mrow[r] = mnew;
#pragma unroll
      for (int d = 0; d < 5; ++d) oacc[d][r] *= resc;
      Plds[w][lg * 4 + r][lr]      = f2bf(p0);
      Plds[w][lg * 4 + r][16 + lr] = f2bf(p1);
    }
    asm volatile("s_waitcnt lgkmcnt(0)" ::: "memory");
    bf16x8 pf = *(const bf16x8*)&Plds[w][lr][lg * 8];
#pragma unroll
    for (int d = 0; d < 5; ++d) {
      bf16x8 vf = *(const bf16x8*)&Vh[(size_t)(d * 16 + lr) * SS + kv0 + lg * 8];
      oacc[d] = __builtin_amdgcn_mfma_f32_16x16x32_bf16(pf, vf, oacc[d], 0, 0, 0);
    }
  }
  const int b = bh >> 5, h = bh & 31;
#pragma unroll
  for (int r = 0; r < 4; ++r) {
    const int qr = q0 + lg * 4 + r;
    const float inv = 1.f / lrow[r];
#pragma unroll
    for (int d = 0; d < 5; ++d)
      O[(size_t)(b * SS + qr) * DD + h * DHH + d * 16 + lr] = f2bf(oacc[d][r] * inv);
  }
}

// ---------------- GEMM: C[M][N] = A[M][K] @ Bt[N][K]^T, m97 structure ----------------
__device__ __forceinline__ float gelu_f(float x) {
  float x3 = x * x * x;
  return 0.5f * x * (1.f + tanhf(0.7978845608028654f * (x + 0.044715f * x3)));
}

// MODE 0: out bf16 = C + bias
// MODE 2: out bf16 = gelu(C + bias)
// MODE 3: out fp32 = C + bias + bf16(addb) + addf
template <int MODE>
__global__ __launch_bounds__(256) void gemm_bt(const unsigned short* __restrict__ A,
                                               const unsigned short* __restrict__ Bt,
                                               const float* __restrict__ bias,
                                               void* __restrict__ Cout,
                                               const unsigned short* __restrict__ addb,
                                               const float* __restrict__ addf,
                                               int M, int N, int K) {
  __shared__ __align__(16) unsigned short As[128 * 32];
  __shared__ __align__(16) unsigned short Bs[128 * 32];
  const int tid = threadIdx.x;
  const int w = tid >> 6, lane = tid & 63;
  const int lr = lane & 15, lg = lane >> 4;
  const int m0 = blockIdx.y * 128, n0 = blockIdx.x * 128;
  const int wm = (w & 1) * 64, wn = (w >> 1) * 64;

  const int srow = tid >> 2;
  const int scol = (tid & 3) * 8;
  const unsigned short* Ag0 = A + (size_t)(m0 + srow) * K + scol;
  const unsigned short* Ag1 = Ag0 + (size_t)64 * K;
  const unsigned short* Bg0 = Bt + (size_t)(n0 + srow) * K + scol;
  const unsigned short* Bg1 = Bg0 + (size_t)64 * K;
  char* AsB = (char*)&As[0];
  char* BsB = (char*)&Bs[0];
  const int ldsoff0 = w * 1024, ldsoff1 = 4096 + w * 1024;

  f32x4 acc[4][4];
#pragma unroll
  for (int i = 0; i < 4; ++i)
#pragma unroll
    for (int j = 0; j < 4; ++j) acc[i][j] = (f32x4){0.f, 0.f, 0.f, 0.f};

  for (int kt = 0; kt < K; kt += 32) {
    gl_lds16(Ag0, AsB + ldsoff0);
    gl_lds16(Ag1, AsB + ldsoff1);
    gl_lds16(Bg0, BsB + ldsoff0);
    gl_lds16(Bg1, BsB + ldsoff1);
    Ag0 += 32; Ag1 += 32; Bg0 += 32; Bg1 += 32;
    __syncthreads();
    bf16x8 af[4], bfm[4];
#pragma unroll
    for (int i = 0; i < 4; ++i) {
      af[i]  = *(const bf16x8*)&As[(wm + i * 16 + lr) * 32 + lg * 8];
      bfm[i] = *(const bf16x8*)&Bs[(wn + i * 16 + lr) * 32 + lg * 8];
    }
#pragma unroll
    for (int i = 0; i < 4; ++i)
#pragma unroll
      for (int j = 0; j < 4; ++j)
        acc[i][j] = __builtin_amdgcn_mfma_f32_16x16x32_bf16(af[i], bfm[j], acc[i][j], 0, 0, 0);
    __syncthreads();
  }

#pragma unroll
  for (int i = 0; i < 4; ++i) {
    const int rb = m0 + wm + i * 16 + lg * 4;
#pragma unroll
    for (int j = 0; j < 4; ++j) {
      const int col = n0 + wn + j * 16 + lr;
      const float bv = bias[col];
#pragma unroll
      for (int r = 0; r < 4; ++r) {
        const size_t idx = (size_t)(rb + r) * N + col;
        float v = acc[i][j][r] + bv;
        if (MODE == 2) v = gelu_f(v);
        if (MODE == 3) {
          ((float*)Cout)[idx] = v + bf2f(addb[idx]) + addf[idx];
        } else {
          ((unsigned short*)Cout)[idx] = f2bf(v);
        }
      }
    }
  }
}

extern "C" void kernel_launch(void* const* d_in, const int* in_sizes, int n_in,
                              void* d_out, int out_size, void* d_ws, size_t ws_size,
                              hipStream_t stream) {
  (void)in_sizes; (void)n_in; (void)out_size; (void)ws_size;
  const float* hidden = (const float*)d_in[1];
  const float* ln_g = (const float*)d_in[2];
  const float* ln_b = (const float*)d_in[3];
  const float* wqkv = (const float*)d_in[4];
  const float* bqkv = (const float*)d_in[5];
  const float* wout = (const float*)d_in[6];
  const float* bout = (const float*)d_in[7];
  const float* wfc1 = (const float*)d_in[8];
  const float* bfc1 = (const float*)d_in[9];
  const float* wfc2 = (const float*)d_in[10];
  const float* bfc2 = (const float*)d_in[11];
  float* out = (float*)d_out;

  char* ws = (char*)d_ws;
  size_t off = 0;
  auto alloc = [&](size_t bytes) -> void* {
    void* p = ws + off;
    off += (bytes + 255) & ~(size_t)255;
    return p;
  };
  unsigned short* wqkvT = (unsigned short*)alloc((size_t)3 * DD * DD * 2);
  unsigned short* woutT = (unsigned short*)alloc((size_t)DD * DD * 2);
  unsigned short* wfc1T = (unsigned short*)alloc((size_t)NII * DD * 2);
  unsigned short* wfc2T = (unsigned short*)alloc((size_t)DD * NII * 2);
  unsigned short* xln   = (unsigned short*)alloc((size_t)NTOK * DD * 2);
  unsigned short* regA  = (unsigned short*)alloc((size_t)NTOK * NII * 2);  // qkv, then h1
  unsigned short* Qp    = (unsigned short*)alloc((size_t)2 * HH * SS * DPAD * 2);  // then attn_proj
  unsigned short* Kp    = (unsigned short*)alloc((size_t)2 * HH * SS * DPAD * 2);
  unsigned short* Vt    = (unsigned short*)alloc((size_t)2 * HH * DHH * SS * 2);
  unsigned short* Obuf  = (unsigned short*)alloc((size_t)NTOK * DD * 2);
  unsigned short* qkvbuf   = regA;
  unsigned short* h1       = regA;
  unsigned short* attnproj = Qp;

  wt_transpose<<<dim3(3 * DD / 32, DD / 32), 256, 0, stream>>>(wqkv, wqkvT, DD, 3 * DD);
  wt_transpose<<<dim3(DD / 32, DD / 32), 256, 0, stream>>>(wout, woutT, DD, DD);
  wt_transpose<<<dim3(NII / 32, DD / 32), 256, 0, stream>>>(wfc1, wfc1T, DD, NII);
  wt_transpose<<<dim3(DD / 32, NII / 32), 256, 0, stream>>>(wfc2, wfc2T, NII, DD);
  ln_kernel<<<NTOK, 256, 0, stream>>>(hidden, ln_g, ln_b, xln);
  gemm_bt<0><<<dim3(3 * DD / 128, NTOK / 128), 256, 0, stream>>>(
      xln, wqkvT, bqkv, qkvbuf, nullptr, nullptr, NTOK, 3 * DD, DD);
  rope_kernel<<<NTOK, 256, 0, stream>>>(qkvbuf, Qp, Kp, Vt);
  attn_kernel<<<dim3(SS / 64, 2 * HH), 256, 0, stream>>>(Qp, Kp, Vt, Obuf);
  gemm_bt<0><<<dim3(DD / 128, NTOK / 128), 256, 0, stream>>>(
      Obuf, woutT, bout, attnproj, nullptr, nullptr, NTOK, DD, DD);
  gemm_bt<2><<<dim3(NII / 128, NTOK / 128), 256, 0, stream>>>(
      xln, wfc1T, bfc1, h1, nullptr, nullptr, NTOK, NII, DD);
  gemm_bt<3><<<dim3(DD / 128, NTOK / 128), 256, 0, stream>>>(
      h1, wfc2T, bfc2, out, attnproj, hidden, NTOK, DD, NII);
}

// Round 2
// 1520.139 us; speedup vs baseline: 1.1831x; 1.1831x over previous
//
#include <hip/hip_runtime.h>

#define SS   2048
#define DD   2560
#define HH   32
#define DHH  80
#define DPAD 96
#define NII  10240
#define NTOK 4096

typedef __attribute__((ext_vector_type(8))) __bf16 bf16x8;
typedef __attribute__((ext_vector_type(4))) float  f32x4;

__device__ __forceinline__ float bf2f(unsigned short h) {
  union { unsigned u; float f; } c; c.u = ((unsigned)h) << 16; return c.f;
}
__device__ __forceinline__ unsigned short f2bf(float f) {
  union { float f; unsigned u; } c; c.f = f;
  unsigned r = c.u + 0x7FFFu + ((c.u >> 16) & 1u);
  return (unsigned short)(r >> 16);
}

__device__ __forceinline__ void gl_lds16(const void* gptr, void* lptr) {
  __builtin_amdgcn_global_load_lds((__attribute__((address_space(1))) void*)gptr,
                                   (__attribute__((address_space(3))) void*)lptr,
                                   16, 0, 0);
}

// ---------------- weight transpose: W[K][N] fp32 -> Wt[N][K] bf16 ----------------
__global__ __launch_bounds__(256) void wt_transpose(const float* __restrict__ W,
                                                    unsigned short* __restrict__ Wt,
                                                    int K, int N) {
  __shared__ float tile[32][33];
  const int tx = threadIdx.x & 31, ty = threadIdx.x >> 5;
  const int n0 = blockIdx.x * 32, k0 = blockIdx.y * 32;
#pragma unroll
  for (int i = 0; i < 32; i += 8)
    tile[ty + i][tx] = W[(size_t)(k0 + ty + i) * N + n0 + tx];
  __syncthreads();
#pragma unroll
  for (int i = 0; i < 32; i += 8)
    Wt[(size_t)(n0 + ty + i) * K + k0 + tx] = f2bf(tile[tx][ty + i]);
}

// ---------------- LayerNorm: fp32 in -> bf16 out ----------------
__global__ __launch_bounds__(256) void ln_kernel(const float* __restrict__ X,
                                                 const float* __restrict__ G,
                                                 const float* __restrict__ Bb,
                                                 unsigned short* __restrict__ Xo) {
  const int row = blockIdx.x;
  const float4* xr = (const float4*)(X + (size_t)row * DD);
  float s = 0.f, ss = 0.f;
  for (int i = threadIdx.x; i < DD / 4; i += 256) {
    float4 v = xr[i];
    s  += v.x + v.y + v.z + v.w;
    ss += v.x * v.x + v.y * v.y + v.z * v.z + v.w * v.w;
  }
#pragma unroll
  for (int o = 32; o > 0; o >>= 1) { s += __shfl_down(s, o, 64); ss += __shfl_down(ss, o, 64); }
  __shared__ float red[8];
  const int w = threadIdx.x >> 6;
  if ((threadIdx.x & 63) == 0) { red[w] = s; red[4 + w] = ss; }
  __syncthreads();
  if (threadIdx.x == 0) {
    float ts  = red[0] + red[1] + red[2] + red[3];
    float tss = red[4] + red[5] + red[6] + red[7];
    float mu  = ts * (1.f / DD);
    float var = tss * (1.f / DD) - mu * mu;
    red[0] = mu; red[1] = rsqrtf(var + 1e-5f);
  }
  __syncthreads();
  const float mu = red[0], rstd = red[1];
  const float4* gr = (const float4*)G;
  const float4* br = (const float4*)Bb;
  for (int i = threadIdx.x; i < DD / 4; i += 256) {
    float4 v = xr[i], g = gr[i], b = br[i];
    ushort4 o;
    o.x = f2bf((v.x - mu) * rstd * g.x + b.x);
    o.y = f2bf((v.y - mu) * rstd * g.y + b.y);
    o.z = f2bf((v.z - mu) * rstd * g.z + b.z);
    o.w = f2bf((v.w - mu) * rstd * g.w + b.w);
    *(ushort4*)&Xo[(size_t)row * DD + i * 4] = o;
  }
}

// ---------------- RoPE + head-layout ----------------
__global__ __launch_bounds__(256) void rope_kernel(const unsigned short* __restrict__ qkv,
                                                   unsigned short* __restrict__ Qp,
                                                   unsigned short* __restrict__ Kp,
                                                   unsigned short* __restrict__ Vt) {
  const int tok = blockIdx.x;
  const int b = tok / SS, s = tok % SS;
  __shared__ float cs[16], sn[16];
  if (threadIdx.x < 16) {
    float inv = powf(10000.f, -(float)threadIdx.x / 16.f);
    float ang = (float)s * inv;
    cs[threadIdx.x] = cosf(ang);
    sn[threadIdx.x] = sinf(ang);
  }
  __syncthreads();
  const unsigned short* row = qkv + (size_t)tok * (3 * DD);
  for (int idx = threadIdx.x; idx < 2 * HH * DPAD; idx += 256) {
    const int which = idx / (HH * DPAD);
    const int rrem  = idx % (HH * DPAD);
    const int h = rrem / DPAD, d = rrem % DPAD;
    float val = 0.f;
    if (d < DHH) {
      const unsigned short* base = row + which * DD + h * DHH;
      if (d < 16) {
        float x1 = bf2f(base[d]), x2 = bf2f(base[d + 16]);
        val = x1 * cs[d] - x2 * sn[d];
      } else if (d < 32) {
        int i2 = d - 16;
        float x1 = bf2f(base[i2]), x2 = bf2f(base[d]);
        val = x2 * cs[i2] + x1 * sn[i2];
      } else {
        val = bf2f(base[d]);
      }
    }
    unsigned short* outp = which ? Kp : Qp;
    outp[(((size_t)b * HH + h) * SS + s) * DPAD + d] = f2bf(val);
  }
  for (int idx = threadIdx.x; idx < DD; idx += 256) {
    const int h = idx / DHH, d = idx % DHH;
    Vt[(((size_t)b * HH + h) * DHH + d) * SS + s] = row[2 * DD + idx];
  }
}

// ---------------- flash attention (causal), per-wave 16 q-rows ----------------
__global__ __launch_bounds__(256) void attn_kernel(const unsigned short* __restrict__ Qp,
                                                   const unsigned short* __restrict__ Kp,
                                                   const unsigned short* __restrict__ Vt,
                                                   unsigned short* __restrict__ O) {
  const int qblk = blockIdx.x, bh = blockIdx.y;
  const int w = threadIdx.x >> 6, lane = threadIdx.x & 63;
  const int lr = lane & 15, lg = lane >> 4;
  const int q0 = qblk * 64 + w * 16;
  const unsigned short* Qh = Qp + (size_t)bh * SS * DPAD;
  const unsigned short* Kh = Kp + (size_t)bh * SS * DPAD;
  const unsigned short* Vh = Vt + (size_t)bh * DHH * SS;
  __shared__ __align__(16) unsigned short Plds[4][16][32];

  bf16x8 qf[3];
#pragma unroll
  for (int c = 0; c < 3; ++c)
    qf[c] = *(const bf16x8*)&Qh[(size_t)(q0 + lr) * DPAD + c * 32 + lg * 8];

  f32x4 oacc[5];
#pragma unroll
  for (int d = 0; d < 5; ++d) oacc[d] = (f32x4){0.f, 0.f, 0.f, 0.f};
  float mrow[4], lrow[4];
#pragma unroll
  for (int r = 0; r < 4; ++r) { mrow[r] = -1e30f; lrow[r] = 0.f; }

  const float scl = 0.11180339887498949f;
  const int nt = (q0 + 15) / 32 + 1;
  for (int t = 0; t < nt; ++t) {
    const int kv0 = t * 32;
    f32x4 s0 = (f32x4){0.f, 0.f, 0.f, 0.f};
    f32x4 s1 = (f32x4){0.f, 0.f, 0.f, 0.f};
#pragma unroll
    for (int c = 0; c < 3; ++c) {
      bf16x8 kf0 = *(const bf16x8*)&Kh[(size_t)(kv0 + lr) * DPAD + c * 32 + lg * 8];
      bf16x8 kf1 = *(const bf16x8*)&Kh[(size_t)(kv0 + 16 + lr) * DPAD + c * 32 + lg * 8];
      s0 = __builtin_amdgcn_mfma_f32_16x16x32_bf16(qf[c], kf0, s0, 0, 0, 0);
      s1 = __builtin_amdgcn_mfma_f32_16x16x32_bf16(qf[c], kf1, s1, 0, 0, 0);
    }
#pragma unroll
    for (int r = 0; r < 4; ++r) {
      const int qr = q0 + lg * 4 + r;
      float v0 = (kv0 + lr > qr)      ? -1e30f : s0[r] * scl;
      float v1 = (kv0 + 16 + lr > qr) ? -1e30f : s1[r] * scl;
      float mx = fmaxf(v0, v1);
#pragma unroll
      for (int mk = 1; mk < 16; mk <<= 1) mx = fmaxf(mx, __shfl_xor(mx, mk, 64));
      const float mnew = fmaxf(mrow[r], mx);
      const float resc = __expf(mrow[r] - mnew);
      const float p0 = __expf(v0 - mnew);
      const float p1 = __expf(v1 - mnew);
      float rs = p0 + p1;
#pragma unroll
      for (int mk = 1; mk < 16; mk <<= 1) rs += __shfl_xor(rs, mk, 64);
      lrow[r] = lrow[r] * resc + rs;
      mrow[r] = mnew;
#pragma unroll
      for (int d = 0; d < 5; ++d) oacc[d][r] *= resc;
      Plds[w][lg * 4 + r][lr]      = f2bf(p0);
      Plds[w][lg * 4 + r][16 + lr] = f2bf(p1);
    }
    asm volatile("s_waitcnt lgkmcnt(0)" ::: "memory");
    bf16x8 pf = *(const bf16x8*)&Plds[w][lr][lg * 8];
#pragma unroll
    for (int d = 0; d < 5; ++d) {
      bf16x8 vf = *(const bf16x8*)&Vh[(size_t)(d * 16 + lr) * SS + kv0 + lg * 8];
      oacc[d] = __builtin_amdgcn_mfma_f32_16x16x32_bf16(pf, vf, oacc[d], 0, 0, 0);
    }
  }
  const int b = bh >> 5, h = bh & 31;
#pragma unroll
  for (int r = 0; r < 4; ++r) {
    const int qr = q0 + lg * 4 + r;
    const float inv = 1.f / lrow[r];
#pragma unroll
    for (int d = 0; d < 5; ++d)
      O[(size_t)(b * SS + qr) * DD + h * DHH + d * 16 + lr] = f2bf(oacc[d][r] * inv);
  }
}

// ---------------- 256x256 GEMM, 8 waves, BK=32, 4-deep LDS pipeline ----------------
__device__ __forceinline__ float gelu_f(float x) {
  float x3 = x * x * x;
  return 0.5f * x * (1.f + tanhf(0.7978845608028654f * (x + 0.044715f * x3)));
}

// MODE 0: out bf16 = C + bias
// MODE 2: out bf16 = gelu(C + bias)
// MODE 3: out fp32 = C + bias + bf16(addb) + addf
template <int MODE>
__global__ __launch_bounds__(512, 2) void gemm256(const unsigned short* __restrict__ A,
                                                  const unsigned short* __restrict__ Bt,
                                                  const float* __restrict__ bias,
                                                  void* __restrict__ Cout,
                                                  const unsigned short* __restrict__ addb,
                                                  const float* __restrict__ addf,
                                                  int M, int N, int K, int nbx) {
  // A tiles: 4 bufs x [256 rows][32 k] bf16 (16KB each) at byte 0
  // B tiles: same at byte 65536. Total 128 KB.
  __shared__ __align__(16) unsigned short smem[65536];
  char* ldsB = (char*)smem;

  // bijective XCD swizzle (m204)
  const int nwg = gridDim.x;
  const int orig = blockIdx.x;
  const int qq = nwg >> 3, rr = nwg & 7;
  const int xcd = orig & 7, loc = orig >> 3;
  const int swz = (xcd < rr ? xcd * (qq + 1) : rr * (qq + 1) + (xcd - rr) * qq) + loc;
  const int by = swz / nbx, bx = swz % nbx;
  const int m0 = by * 256, n0 = bx * 256;

  const int tid = threadIdx.x;
  const int w = tid >> 6, lane = tid & 63;
  const int lr = lane & 15, lg = lane >> 4;
  const int wm = w & 1, wn = w >> 1;

  // staging: per wave 2 chunks of 1KB per matrix; linear LDS dest, pre-swizzled source.
  // dest byte d (within 16KB tile): row = d>>6, slot = (d>>4)&3 ; src k-slot = slot ^ ((row>>1)&3)
  const int srow = w * 32 + (lane >> 2);           // i=0 rows; i=1 adds 16
  const int sslot = ((lane & 3) ^ ((lane >> 3) & 3)) * 8;  // ((row>>1)&3)==(lane>>3)&3
  const unsigned short* aS0 = A  + (size_t)(m0 + srow) * K + sslot;
  const unsigned short* aS1 = A  + (size_t)(m0 + srow + 16) * K + sslot;
  const unsigned short* bS0 = Bt + (size_t)(n0 + srow) * K + sslot;
  const unsigned short* bS1 = Bt + (size_t)(n0 + srow + 16) * K + sslot;
  const int adest = w * 2048;  // wave-uniform LDS byte base within a tile

  // fragment read: row = base + lr ; swizzled slot = lg ^ ((lr>>1)&3)
  const int fslot = ((lg ^ ((lr >> 1) & 3)) << 4);
  const int arow = wm * 128 + lr;   // + m*16
  const int brow = wn * 64 + lr;    // + n*16

  f32x4 acc[8][4];
#pragma unroll
  for (int i = 0; i < 8; ++i)
#pragma unroll
    for (int j = 0; j < 4; ++j) acc[i][j] = (f32x4){0.f, 0.f, 0.f, 0.f};

  const int nt = K >> 5;

#define STAGE_A(t)                                                        \
  { int _b = (t) & 3;                                                     \
    gl_lds16(aS0 + (size_t)(t) * 32, ldsB + _b * 16384 + adest);          \
    gl_lds16(aS1 + (size_t)(t) * 32, ldsB + _b * 16384 + adest + 1024); }
#define STAGE_B(t)                                                        \
  { int _b = (t) & 3;                                                     \
    gl_lds16(bS0 + (size_t)(t) * 32, ldsB + 65536 + _b * 16384 + adest);  \
    gl_lds16(bS1 + (size_t)(t) * 32, ldsB + 65536 + _b * 16384 + adest + 1024); }
#define LDA(t, m) (*(const bf16x8*)(ldsB + ((t) & 3) * 16384 + (arow + (m) * 16) * 64 + fslot))
#define LDB(t, n) (*(const bf16x8*)(ldsB + 65536 + ((t) & 3) * 16384 + (brow + (n) * 16) * 64 + fslot))

  // prologue: stage tiles 0,1,2 (12 loads); wait for tile 0 (leave 8 in flight)
  STAGE_A(0); STAGE_B(0);
  STAGE_A(1); STAGE_B(1);
  STAGE_A(2); STAGE_B(2);
  asm volatile("s_waitcnt vmcnt(8)" ::: "memory");
  __builtin_amdgcn_s_barrier();
  __builtin_amdgcn_sched_barrier(0);

  for (int t = 0; t < nt; ++t) {
    // ---- phase 0: fragments for m0-3 x all n, stage next A ----
    bf16x8 b0 = LDB(t, 0), b1 = LDB(t, 1), b2 = LDB(t, 2), b3 = LDB(t, 3);
    bf16x8 a0 = LDA(t, 0), a1 = LDA(t, 1), a2 = LDA(t, 2), a3 = LDA(t, 3);
    if (t + 3 < nt) STAGE_A(t + 3);
    __builtin_amdgcn_s_barrier();
    __builtin_amdgcn_s_setprio(1);
    acc[0][0] = __builtin_amdgcn_mfma_f32_16x16x32_bf16(a0, b0, acc[0][0], 0, 0, 0);
    acc[0][1] = __builtin_amdgcn_mfma_f32_16x16x32_bf16(a0, b1, acc[0][1], 0, 0, 0);
    acc[0][2] = __builtin_amdgcn_mfma_f32_16x16x32_bf16(a0, b2, acc[0][2], 0, 0, 0);
    acc[0][3] = __builtin_amdgcn_mfma_f32_16x16x32_bf16(a0, b3, acc[0][3], 0, 0, 0);
    acc[1][0] = __builtin_amdgcn_mfma_f32_16x16x32_bf16(a1, b0, acc[1][0], 0, 0, 0);
    acc[1][1] = __builtin_amdgcn_mfma_f32_16x16x32_bf16(a1, b1, acc[1][1], 0, 0, 0);
    acc[1][2] = __builtin_amdgcn_mfma_f32_16x16x32_bf16(a1, b2, acc[1][2], 0, 0, 0);
    acc[1][3] = __builtin_amdgcn_mfma_f32_16x16x32_bf16(a1, b3, acc[1][3], 0, 0, 0);
    acc[2][0] = __builtin_amdgcn_mfma_f32_16x16x32_bf16(a2, b0, acc[2][0], 0, 0, 0);
    acc[2][1] = __builtin_amdgcn_mfma_f32_16x16x32_bf16(a2, b1, acc[2][1], 0, 0, 0);
    acc[2][2] = __builtin_amdgcn_mfma_f32_16x16x32_bf16(a2, b2, acc[2][2], 0, 0, 0);
    acc[2][3] = __builtin_amdgcn_mfma_f32_16x16x32_bf16(a2, b3, acc[2][3], 0, 0, 0);
    acc[3][0] = __builtin_amdgcn_mfma_f32_16x16x32_bf16(a3, b0, acc[3][0], 0, 0, 0);
    acc[3][1] = __builtin_amdgcn_mfma_f32_16x16x32_bf16(a3, b1, acc[3][1], 0, 0, 0);
    acc[3][2] = __builtin_amdgcn_mfma_f32_16x16x32_bf16(a3, b2, acc[3][2], 0, 0, 0);
    acc[3][3] = __builtin_amdgcn_mfma_f32_16x16x32_bf16(a3, b3, acc[3][3], 0, 0, 0);
    __builtin_amdgcn_s_setprio(0);
    __builtin_amdgcn_s_barrier();
    // ---- phase 1: fragments for m4-7, stage next B ----
    a0 = LDA(t, 4); a1 = LDA(t, 5); a2 = LDA(t, 6); a3 = LDA(t, 7);
    if (t + 3 < nt) STAGE_B(t + 3);
    __builtin_amdgcn_s_barrier();
    __builtin_amdgcn_s_setprio(1);
    acc[4][0] = __builtin_amdgcn_mfma_f32_16x16x32_bf16(a0, b0, acc[4][0], 0, 0, 0);
    acc[4][1] = __builtin_amdgcn_mfma_f32_16x16x32_bf16(a0, b1, acc[4][1], 0, 0, 0);
    acc[4][2] = __builtin_amdgcn_mfma_f32_16x16x32_bf16(a0, b2, acc[4][2], 0, 0, 0);
    acc[4][3] = __builtin_amdgcn_mfma_f32_16x16x32_bf16(a0, b3, acc[4][3], 0, 0, 0);
    acc[5][0] = __builtin_amdgcn_mfma_f32_16x16x32_bf16(a1, b0, acc[5][0], 0, 0, 0);
    acc[5][1] = __builtin_amdgcn_mfma_f32_16x16x32_bf16(a1, b1, acc[5][1], 0, 0, 0);
    acc[5][2] = __builtin_amdgcn_mfma_f32_16x16x32_bf16(a1, b2, acc[5][2], 0, 0, 0);
    acc[5][3] = __builtin_amdgcn_mfma_f32_16x16x32_bf16(a1, b3, acc[5][3], 0, 0, 0);
    acc[6][0] = __builtin_amdgcn_mfma_f32_16x16x32_bf16(a2, b0, acc[6][0], 0, 0, 0);
    acc[6][1] = __builtin_amdgcn_mfma_f32_16x16x32_bf16(a2, b1, acc[6][1], 0, 0, 0);
    acc[6][2] = __builtin_amdgcn_mfma_f32_16x16x32_bf16(a2, b2, acc[6][2], 0, 0, 0);
    acc[6][3] = __builtin_amdgcn_mfma_f32_16x16x32_bf16(a2, b3, acc[6][3], 0, 0, 0);
    acc[7][0] = __builtin_amdgcn_mfma_f32_16x16x32_bf16(a3, b0, acc[7][0], 0, 0, 0);
    acc[7][1] = __builtin_amdgcn_mfma_f32_16x16x32_bf16(a3, b1, acc[7][1], 0, 0, 0);
    acc[7][2] = __builtin_amdgcn_mfma_f32_16x16x32_bf16(a3, b2, acc[7][2], 0, 0, 0);
    acc[7][3] = __builtin_amdgcn_mfma_f32_16x16x32_bf16(a3, b3, acc[7][3], 0, 0, 0);
    __builtin_amdgcn_s_setprio(0);
    // ---- tile boundary: counted vmcnt (8 steady / 4 / 0 at tail) ----
    const int rem = nt - 2 - t;
    if (rem >= 2)      asm volatile("s_waitcnt vmcnt(8)" ::: "memory");
    else if (rem == 1) asm volatile("s_waitcnt vmcnt(4)" ::: "memory");
    else               asm volatile("s_waitcnt vmcnt(0)" ::: "memory");
    __builtin_amdgcn_s_barrier();
    __builtin_amdgcn_sched_barrier(0);
  }
#undef STAGE_A
#undef STAGE_B
#undef LDA
#undef LDB

  // epilogue
#pragma unroll
  for (int m = 0; m < 8; ++m) {
    const int rb = m0 + wm * 128 + m * 16 + lg * 4;
#pragma unroll
    for (int n = 0; n < 4; ++n) {
      const int col = n0 + wn * 64 + n * 16 + lr;
      const float bv = bias[col];
#pragma unroll
      for (int r = 0; r < 4; ++r) {
        const size_t idx = (size_t)(rb + r) * N + col;
        float v = acc[m][n][r] + bv;
        if (MODE == 2) v = gelu_f(v);
        if (MODE == 3) {
          ((float*)Cout)[idx] = v + bf2f(addb[idx]) + addf[idx];
        } else {
          ((unsigned short*)Cout)[idx] = f2bf(v);
        }
      }
    }
  }
}

extern "C" void kernel_launch(void* const* d_in, const int* in_sizes, int n_in,
                              void* d_out, int out_size, void* d_ws, size_t ws_size,
                              hipStream_t stream) {
  (void)in_sizes; (void)n_in; (void)out_size; (void)ws_size;
  const float* hidden = (const float*)d_in[1];
  const float* ln_g = (const float*)d_in[2];
  const float* ln_b = (const float*)d_in[3];
  const float* wqkv = (const float*)d_in[4];
  const float* bqkv = (const float*)d_in[5];
  const float* wout = (const float*)d_in[6];
  const float* bout = (const float*)d_in[7];
  const float* wfc1 = (const float*)d_in[8];
  const float* bfc1 = (const float*)d_in[9];
  const float* wfc2 = (const float*)d_in[10];
  const float* bfc2 = (const float*)d_in[11];
  float* out = (float*)d_out;

  char* ws = (char*)d_ws;
  size_t off = 0;
  auto alloc = [&](size_t bytes) -> void* {
    void* p = ws + off;
    off += (bytes + 255) & ~(size_t)255;
    return p;
  };
  unsigned short* wqkvT = (unsigned short*)alloc((size_t)3 * DD * DD * 2);
  unsigned short* woutT = (unsigned short*)alloc((size_t)DD * DD * 2);
  unsigned short* wfc1T = (unsigned short*)alloc((size_t)NII * DD * 2);
  unsigned short* wfc2T = (unsigned short*)alloc((size_t)DD * NII * 2);
  unsigned short* xln   = (unsigned short*)alloc((size_t)NTOK * DD * 2);
  unsigned short* regA  = (unsigned short*)alloc((size_t)NTOK * NII * 2);  // qkv, then h1
  unsigned short* Qp    = (unsigned short*)alloc((size_t)2 * HH * SS * DPAD * 2);  // then attn_proj
  unsigned short* Kp    = (unsigned short*)alloc((size_t)2 * HH * SS * DPAD * 2);
  unsigned short* Vt    = (unsigned short*)alloc((size_t)2 * HH * DHH * SS * 2);
  unsigned short* Obuf  = (unsigned short*)alloc((size_t)NTOK * DD * 2);
  unsigned short* qkvbuf   = regA;
  unsigned short* h1       = regA;
  unsigned short* attnproj = Qp;

  wt_transpose<<<dim3(3 * DD / 32, DD / 32), 256, 0, stream>>>(wqkv, wqkvT, DD, 3 * DD);
  wt_transpose<<<dim3(DD / 32, DD / 32), 256, 0, stream>>>(wout, woutT, DD, DD);
  wt_transpose<<<dim3(NII / 32, DD / 32), 256, 0, stream>>>(wfc1, wfc1T, DD, NII);
  wt_transpose<<<dim3(DD / 32, NII / 32), 256, 0, stream>>>(wfc2, wfc2T, NII, DD);
  ln_kernel<<<NTOK, 256, 0, stream>>>(hidden, ln_g, ln_b, xln);
  gemm256<0><<<dim3((3 * DD / 256) * (NTOK / 256)), 512, 0, stream>>>(
      xln, wqkvT, bqkv, qkvbuf, nullptr, nullptr, NTOK, 3 * DD, DD, 3 * DD / 256);
  rope_kernel<<<NTOK, 256, 0, stream>>>(qkvbuf, Qp, Kp, Vt);
  attn_kernel<<<dim3(SS / 64, 2 * HH), 256, 0, stream>>>(Qp, Kp, Vt, Obuf);
  gemm256<0><<<dim3((DD / 256) * (NTOK / 256)), 512, 0, stream>>>(
      Obuf, woutT, bout, attnproj, nullptr, nullptr, NTOK, DD, DD, DD / 256);
  gemm256<2><<<dim3((NII / 256) * (NTOK / 256)), 512, 0, stream>>>(
      xln, wfc1T, bfc1, h1, nullptr, nullptr, NTOK, NII, DD, NII / 256);
  gemm256<3><<<dim3((DD / 256) * (NTOK / 256)), 512, 0, stream>>>(
      h1, wfc2T, bfc2, out, attnproj, hidden, NTOK, DD, NII, DD / 256);
}

// Round 3
// 1325.910 us; speedup vs baseline: 1.3564x; 1.1465x over previous
//
#include <hip/hip_runtime.h>

#define SS   2048
#define DD   2560
#define HH   32
#define DHH  80
#define DPAD 96
#define NII  10240
#define NTOK 4096

typedef __attribute__((ext_vector_type(8))) __bf16 bf16x8;
typedef __attribute__((ext_vector_type(4))) float  f32x4;

__device__ __forceinline__ float bf2f(unsigned short h) {
  union { unsigned u; float f; } c; c.u = ((unsigned)h) << 16; return c.f;
}
__device__ __forceinline__ unsigned short f2bf(float f) {
  union { float f; unsigned u; } c; c.f = f;
  unsigned r = c.u + 0x7FFFu + ((c.u >> 16) & 1u);
  return (unsigned short)(r >> 16);
}

__device__ __forceinline__ void gl_lds16(const void* gptr, void* lptr) {
  __builtin_amdgcn_global_load_lds((__attribute__((address_space(1))) void*)gptr,
                                   (__attribute__((address_space(3))) void*)lptr,
                                   16, 0, 0);
}

// ---------------- weight transpose: W[K][N] fp32 -> Wt[N][K] bf16 ----------------
__global__ __launch_bounds__(256) void wt_transpose(const float* __restrict__ W,
                                                    unsigned short* __restrict__ Wt,
                                                    int K, int N) {
  __shared__ float tile[32][33];
  const int tx = threadIdx.x & 31, ty = threadIdx.x >> 5;
  const int n0 = blockIdx.x * 32, k0 = blockIdx.y * 32;
#pragma unroll
  for (int i = 0; i < 32; i += 8)
    tile[ty + i][tx] = W[(size_t)(k0 + ty + i) * N + n0 + tx];
  __syncthreads();
#pragma unroll
  for (int i = 0; i < 32; i += 8)
    Wt[(size_t)(n0 + ty + i) * K + k0 + tx] = f2bf(tile[tx][ty + i]);
}

// ---------------- LayerNorm: fp32 in -> bf16 out ----------------
__global__ __launch_bounds__(256) void ln_kernel(const float* __restrict__ X,
                                                 const float* __restrict__ G,
                                                 const float* __restrict__ Bb,
                                                 unsigned short* __restrict__ Xo) {
  const int row = blockIdx.x;
  const float4* xr = (const float4*)(X + (size_t)row * DD);
  float s = 0.f, ss = 0.f;
  for (int i = threadIdx.x; i < DD / 4; i += 256) {
    float4 v = xr[i];
    s  += v.x + v.y + v.z + v.w;
    ss += v.x * v.x + v.y * v.y + v.z * v.z + v.w * v.w;
  }
#pragma unroll
  for (int o = 32; o > 0; o >>= 1) { s += __shfl_down(s, o, 64); ss += __shfl_down(ss, o, 64); }
  __shared__ float red[8];
  const int w = threadIdx.x >> 6;
  if ((threadIdx.x & 63) == 0) { red[w] = s; red[4 + w] = ss; }
  __syncthreads();
  if (threadIdx.x == 0) {
    float ts  = red[0] + red[1] + red[2] + red[3];
    float tss = red[4] + red[5] + red[6] + red[7];
    float mu  = ts * (1.f / DD);
    float var = tss * (1.f / DD) - mu * mu;
    red[0] = mu; red[1] = rsqrtf(var + 1e-5f);
  }
  __syncthreads();
  const float mu = red[0], rstd = red[1];
  const float4* gr = (const float4*)G;
  const float4* br = (const float4*)Bb;
  for (int i = threadIdx.x; i < DD / 4; i += 256) {
    float4 v = xr[i], g = gr[i], b = br[i];
    ushort4 o;
    o.x = f2bf((v.x - mu) * rstd * g.x + b.x);
    o.y = f2bf((v.y - mu) * rstd * g.y + b.y);
    o.z = f2bf((v.z - mu) * rstd * g.z + b.z);
    o.w = f2bf((v.w - mu) * rstd * g.w + b.w);
    *(ushort4*)&Xo[(size_t)row * DD + i * 4] = o;
  }
}

// ---------------- RoPE + head-layout ----------------
__global__ __launch_bounds__(256) void rope_kernel(const unsigned short* __restrict__ qkv,
                                                   unsigned short* __restrict__ Qp,
                                                   unsigned short* __restrict__ Kp,
                                                   unsigned short* __restrict__ Vt) {
  const int tok = blockIdx.x;
  const int b = tok / SS, s = tok % SS;
  __shared__ float cs[16], sn[16];
  if (threadIdx.x < 16) {
    float inv = powf(10000.f, -(float)threadIdx.x / 16.f);
    float ang = (float)s * inv;
    cs[threadIdx.x] = cosf(ang);
    sn[threadIdx.x] = sinf(ang);
  }
  __syncthreads();
  const unsigned short* row = qkv + (size_t)tok * (3 * DD);
  for (int idx = threadIdx.x; idx < 2 * HH * DPAD; idx += 256) {
    const int which = idx / (HH * DPAD);
    const int rrem  = idx % (HH * DPAD);
    const int h = rrem / DPAD, d = rrem % DPAD;
    float val = 0.f;
    if (d < DHH) {
      const unsigned short* base = row + which * DD + h * DHH;
      if (d < 16) {
        float x1 = bf2f(base[d]), x2 = bf2f(base[d + 16]);
        val = x1 * cs[d] - x2 * sn[d];
      } else if (d < 32) {
        int i2 = d - 16;
        float x1 = bf2f(base[i2]), x2 = bf2f(base[d]);
        val = x2 * cs[i2] + x1 * sn[i2];
      } else {
        val = bf2f(base[d]);
      }
    }
    unsigned short* outp = which ? Kp : Qp;
    outp[(((size_t)b * HH + h) * SS + s) * DPAD + d] = f2bf(val);
  }
  for (int idx = threadIdx.x; idx < DD; idx += 256) {
    const int h = idx / DHH, d = idx % DHH;
    Vt[(((size_t)b * HH + h) * DHH + d) * SS + s] = row[2 * DD + idx];
  }
}

// ---------------- flash attention (causal), 2-wave blocks, 16 q-rows/wave, KVBLK=64 ----------------
// Heavy-first LPT dispatch: blockIdx 0 gets the longest (largest q) tiles.
__global__ __launch_bounds__(128) void attn_kernel(const unsigned short* __restrict__ Qp,
                                                   const unsigned short* __restrict__ Kp,
                                                   const unsigned short* __restrict__ Vt,
                                                   unsigned short* __restrict__ O) {
  const int bid = blockIdx.x;
  const int bh = bid & 63;
  const int p = 63 - (bid >> 6);        // heavy first
  const int w = threadIdx.x >> 6;
  const int tile = p * 2 + w;           // q-tile of 16 rows, tile in [0,128)
  const int lane = threadIdx.x & 63;
  const int lr = lane & 15, lg = lane >> 4;
  const int q0 = tile * 16;
  const unsigned short* Qh = Qp + (size_t)bh * SS * DPAD;
  const unsigned short* Kh = Kp + (size_t)bh * SS * DPAD;
  const unsigned short* Vh = Vt + (size_t)bh * DHH * SS;
  __shared__ __align__(16) char Plds[2][2048];  // per-wave P tile [16][64] bf16, XOR-swizzled
  char* Pb = Plds[w];

  bf16x8 qf[3];
#pragma unroll
  for (int c = 0; c < 3; ++c)
    qf[c] = *(const bf16x8*)&Qh[(size_t)(q0 + lr) * DPAD + c * 32 + lg * 8];

  f32x4 oacc[5];
#pragma unroll
  for (int d = 0; d < 5; ++d) oacc[d] = (f32x4){0.f, 0.f, 0.f, 0.f};
  float mrow[4], lrow[4];
#pragma unroll
  for (int r = 0; r < 4; ++r) { mrow[r] = -1e30f; lrow[r] = 0.f; }

  const float scl = 0.11180339887498949f;  // 80^-0.5
  const int nt = q0 / 64 + 1;
  for (int t = 0; t < nt; ++t) {
    const int kv0 = t * 64;
    f32x4 s0 = (f32x4){0.f, 0.f, 0.f, 0.f};
    f32x4 s1 = (f32x4){0.f, 0.f, 0.f, 0.f};
    f32x4 s2 = (f32x4){0.f, 0.f, 0.f, 0.f};
    f32x4 s3 = (f32x4){0.f, 0.f, 0.f, 0.f};
#pragma unroll
    for (int c = 0; c < 3; ++c) {
      bf16x8 k0 = *(const bf16x8*)&Kh[(size_t)(kv0 +      lr) * DPAD + c * 32 + lg * 8];
      bf16x8 k1 = *(const bf16x8*)&Kh[(size_t)(kv0 + 16 + lr) * DPAD + c * 32 + lg * 8];
      bf16x8 k2 = *(const bf16x8*)&Kh[(size_t)(kv0 + 32 + lr) * DPAD + c * 32 + lg * 8];
      bf16x8 k3 = *(const bf16x8*)&Kh[(size_t)(kv0 + 48 + lr) * DPAD + c * 32 + lg * 8];
      s0 = __builtin_amdgcn_mfma_f32_16x16x32_bf16(qf[c], k0, s0, 0, 0, 0);
      s1 = __builtin_amdgcn_mfma_f32_16x16x32_bf16(qf[c], k1, s1, 0, 0, 0);
      s2 = __builtin_amdgcn_mfma_f32_16x16x32_bf16(qf[c], k2, s2, 0, 0, 0);
      s3 = __builtin_amdgcn_mfma_f32_16x16x32_bf16(qf[c], k3, s3, 0, 0, 0);
    }
    // masked, scaled scores: pv[r][f]
    float pv0[4], pv1[4], pv2[4], pv3[4], mx[4];
    bool need = false;
#pragma unroll
    for (int r = 0; r < 4; ++r) {
      const int qr = q0 + lg * 4 + r;
      float a0 = (kv0 +      lr > qr) ? -1e30f : s0[r] * scl;
      float a1 = (kv0 + 16 + lr > qr) ? -1e30f : s1[r] * scl;
      float a2 = (kv0 + 32 + lr > qr) ? -1e30f : s2[r] * scl;
      float a3 = (kv0 + 48 + lr > qr) ? -1e30f : s3[r] * scl;
      pv0[r] = a0; pv1[r] = a1; pv2[r] = a2; pv3[r] = a3;
      float m = fmaxf(fmaxf(a0, a1), fmaxf(a2, a3));
#pragma unroll
      for (int mk = 1; mk < 16; mk <<= 1) m = fmaxf(m, __shfl_xor(m, mk, 64));
      mx[r] = m;
      need = need || (m > mrow[r] + 8.f);
    }
    if (__ballot(need)) {  // defer-max: rescale only when a row's max grew past THR=8
#pragma unroll
      for (int r = 0; r < 4; ++r) {
        float mnew = fmaxf(mrow[r], mx[r]);
        float resc = __expf(mrow[r] - mnew);
        lrow[r] *= resc;
#pragma unroll
        for (int d = 0; d < 5; ++d) oacc[d][r] *= resc;
        mrow[r] = mnew;
      }
    }
#pragma unroll
    for (int r = 0; r < 4; ++r) {
      const int row = lg * 4 + r;
      const int swz = (row & 7) << 4;
      float p0 = __expf(pv0[r] - mrow[r]);
      float p1 = __expf(pv1[r] - mrow[r]);
      float p2 = __expf(pv2[r] - mrow[r]);
      float p3 = __expf(pv3[r] - mrow[r]);
      *(unsigned short*)(Pb + row * 128 + ((( 0 + lr) * 2) ^ swz)) = f2bf(p0);
      *(unsigned short*)(Pb + row * 128 + (((16 + lr) * 2) ^ swz)) = f2bf(p1);
      *(unsigned short*)(Pb + row * 128 + (((32 + lr) * 2) ^ swz)) = f2bf(p2);
      *(unsigned short*)(Pb + row * 128 + (((48 + lr) * 2) ^ swz)) = f2bf(p3);
      float rs = (p0 + p1) + (p2 + p3);
#pragma unroll
      for (int mk = 1; mk < 16; mk <<= 1) rs += __shfl_xor(rs, mk, 64);
      lrow[r] += rs;
    }
    asm volatile("s_waitcnt lgkmcnt(0)" ::: "memory");
    const int rswz = (lr & 7) << 4;
    bf16x8 pa0 = *(const bf16x8*)(Pb + lr * 128 + ((lg * 16) ^ rswz));
    bf16x8 pa1 = *(const bf16x8*)(Pb + lr * 128 + ((64 + lg * 16) ^ rswz));
#pragma unroll
    for (int d = 0; d < 5; ++d) {
      bf16x8 v0 = *(const bf16x8*)&Vh[(size_t)(d * 16 + lr) * SS + kv0 + lg * 8];
      bf16x8 v1 = *(const bf16x8*)&Vh[(size_t)(d * 16 + lr) * SS + kv0 + 32 + lg * 8];
      oacc[d] = __builtin_amdgcn_mfma_f32_16x16x32_bf16(pa0, v0, oacc[d], 0, 0, 0);
      oacc[d] = __builtin_amdgcn_mfma_f32_16x16x32_bf16(pa1, v1, oacc[d], 0, 0, 0);
    }
  }
  const int b = bh >> 5, h = bh & 31;
#pragma unroll
  for (int r = 0; r < 4; ++r) {
    const int qr = q0 + lg * 4 + r;
    const float inv = 1.f / lrow[r];
#pragma unroll
    for (int d = 0; d < 5; ++d)
      O[(size_t)(b * SS + qr) * DD + h * DHH + d * 16 + lr] = f2bf(oacc[d][r] * inv);
  }
}

// ---------------- 256x256 GEMM, 8 waves, BK=32, 4-deep LDS pipeline ----------------
__device__ __forceinline__ float gelu_f(float x) {
  float x3 = x * x * x;
  return 0.5f * x * (1.f + tanhf(0.7978845608028654f * (x + 0.044715f * x3)));
}

// MODE 0: out bf16 = C + bias
// MODE 2: out bf16 = gelu(C + bias)
// MODE 3: out fp32 = C + bias + bf16(addb) + addf
template <int MODE>
__global__ __launch_bounds__(512, 2) void gemm256(const unsigned short* __restrict__ A,
                                                  const unsigned short* __restrict__ Bt,
                                                  const float* __restrict__ bias,
                                                  void* __restrict__ Cout,
                                                  const unsigned short* __restrict__ addb,
                                                  const float* __restrict__ addf,
                                                  int M, int N, int K, int nbx) {
  __shared__ __align__(16) unsigned short smem[65536];
  char* ldsB = (char*)smem;

  const int nwg = gridDim.x;
  const int orig = blockIdx.x;
  const int qq = nwg >> 3, rr = nwg & 7;
  const int xcd = orig & 7, loc = orig >> 3;
  const int swz = (xcd < rr ? xcd * (qq + 1) : rr * (qq + 1) + (xcd - rr) * qq) + loc;
  const int by = swz / nbx, bx = swz % nbx;
  const int m0 = by * 256, n0 = bx * 256;

  const int tid = threadIdx.x;
  const int w = tid >> 6, lane = tid & 63;
  const int lr = lane & 15, lg = lane >> 4;
  const int wm = w & 1, wn = w >> 1;

  const int srow = w * 32 + (lane >> 2);
  const int sslot = ((lane & 3) ^ ((lane >> 3) & 3)) * 8;
  const unsigned short* aS0 = A  + (size_t)(m0 + srow) * K + sslot;
  const unsigned short* aS1 = A  + (size_t)(m0 + srow + 16) * K + sslot;
  const unsigned short* bS0 = Bt + (size_t)(n0 + srow) * K + sslot;
  const unsigned short* bS1 = Bt + (size_t)(n0 + srow + 16) * K + sslot;
  const int adest = w * 2048;

  const int fslot = ((lg ^ ((lr >> 1) & 3)) << 4);
  const int arow = wm * 128 + lr;
  const int brow = wn * 64 + lr;

  f32x4 acc[8][4];
#pragma unroll
  for (int i = 0; i < 8; ++i)
#pragma unroll
    for (int j = 0; j < 4; ++j) acc[i][j] = (f32x4){0.f, 0.f, 0.f, 0.f};

  const int nt = K >> 5;

#define STAGE_A(t)                                                        \
  { int _b = (t) & 3;                                                     \
    gl_lds16(aS0 + (size_t)(t) * 32, ldsB + _b * 16384 + adest);          \
    gl_lds16(aS1 + (size_t)(t) * 32, ldsB + _b * 16384 + adest + 1024); }
#define STAGE_B(t)                                                        \
  { int _b = (t) & 3;                                                     \
    gl_lds16(bS0 + (size_t)(t) * 32, ldsB + 65536 + _b * 16384 + adest);  \
    gl_lds16(bS1 + (size_t)(t) * 32, ldsB + 65536 + _b * 16384 + adest + 1024); }
#define LDA(t, m) (*(const bf16x8*)(ldsB + ((t) & 3) * 16384 + (arow + (m) * 16) * 64 + fslot))
#define LDB(t, n) (*(const bf16x8*)(ldsB + 65536 + ((t) & 3) * 16384 + (brow + (n) * 16) * 64 + fslot))

  STAGE_A(0); STAGE_B(0);
  STAGE_A(1); STAGE_B(1);
  STAGE_A(2); STAGE_B(2);
  asm volatile("s_waitcnt vmcnt(8)" ::: "memory");
  __builtin_amdgcn_s_barrier();
  __builtin_amdgcn_sched_barrier(0);

  for (int t = 0; t < nt; ++t) {
    bf16x8 b0 = LDB(t, 0), b1 = LDB(t, 1), b2 = LDB(t, 2), b3 = LDB(t, 3);
    bf16x8 a0 = LDA(t, 0), a1 = LDA(t, 1), a2 = LDA(t, 2), a3 = LDA(t, 3);
    if (t + 3 < nt) STAGE_A(t + 3);
    __builtin_amdgcn_s_barrier();
    __builtin_amdgcn_s_setprio(1);
    acc[0][0] = __builtin_amdgcn_mfma_f32_16x16x32_bf16(a0, b0, acc[0][0], 0, 0, 0);
    acc[0][1] = __builtin_amdgcn_mfma_f32_16x16x32_bf16(a0, b1, acc[0][1], 0, 0, 0);
    acc[0][2] = __builtin_amdgcn_mfma_f32_16x16x32_bf16(a0, b2, acc[0][2], 0, 0, 0);
    acc[0][3] = __builtin_amdgcn_mfma_f32_16x16x32_bf16(a0, b3, acc[0][3], 0, 0, 0);
    acc[1][0] = __builtin_amdgcn_mfma_f32_16x16x32_bf16(a1, b0, acc[1][0], 0, 0, 0);
    acc[1][1] = __builtin_amdgcn_mfma_f32_16x16x32_bf16(a1, b1, acc[1][1], 0, 0, 0);
    acc[1][2] = __builtin_amdgcn_mfma_f32_16x16x32_bf16(a1, b2, acc[1][2], 0, 0, 0);
    acc[1][3] = __builtin_amdgcn_mfma_f32_16x16x32_bf16(a1, b3, acc[1][3], 0, 0, 0);
    acc[2][0] = __builtin_amdgcn_mfma_f32_16x16x32_bf16(a2, b0, acc[2][0], 0, 0, 0);
    acc[2][1] = __builtin_amdgcn_mfma_f32_16x16x32_bf16(a2, b1, acc[2][1], 0, 0, 0);
    acc[2][2] = __builtin_amdgcn_mfma_f32_16x16x32_bf16(a2, b2, acc[2][2], 0, 0, 0);
    acc[2][3] = __builtin_amdgcn_mfma_f32_16x16x32_bf16(a2, b3, acc[2][3], 0, 0, 0);
    acc[3][0] = __builtin_amdgcn_mfma_f32_16x16x32_bf16(a3, b0, acc[3][0], 0, 0, 0);
    acc[3][1] = __builtin_amdgcn_mfma_f32_16x16x32_bf16(a3, b1, acc[3][1], 0, 0, 0);
    acc[3][2] = __builtin_amdgcn_mfma_f32_16x16x32_bf16(a3, b2, acc[3][2], 0, 0, 0);
    acc[3][3] = __builtin_amdgcn_mfma_f32_16x16x32_bf16(a3, b3, acc[3][3], 0, 0, 0);
    __builtin_amdgcn_s_setprio(0);
    __builtin_amdgcn_s_barrier();
    a0 = LDA(t, 4); a1 = LDA(t, 5); a2 = LDA(t, 6); a3 = LDA(t, 7);
    if (t + 3 < nt) STAGE_B(t + 3);
    __builtin_amdgcn_s_barrier();
    __builtin_amdgcn_s_setprio(1);
    acc[4][0] = __builtin_amdgcn_mfma_f32_16x16x32_bf16(a0, b0, acc[4][0], 0, 0, 0);
    acc[4][1] = __builtin_amdgcn_mfma_f32_16x16x32_bf16(a0, b1, acc[4][1], 0, 0, 0);
    acc[4][2] = __builtin_amdgcn_mfma_f32_16x16x32_bf16(a0, b2, acc[4][2], 0, 0, 0);
    acc[4][3] = __builtin_amdgcn_mfma_f32_16x16x32_bf16(a0, b3, acc[4][3], 0, 0, 0);
    acc[5][0] = __builtin_amdgcn_mfma_f32_16x16x32_bf16(a1, b0, acc[5][0], 0, 0, 0);
    acc[5][1] = __builtin_amdgcn_mfma_f32_16x16x32_bf16(a1, b1, acc[5][1], 0, 0, 0);
    acc[5][2] = __builtin_amdgcn_mfma_f32_16x16x32_bf16(a1, b2, acc[5][2], 0, 0, 0);
    acc[5][3] = __builtin_amdgcn_mfma_f32_16x16x32_bf16(a1, b3, acc[5][3], 0, 0, 0);
    acc[6][0] = __builtin_amdgcn_mfma_f32_16x16x32_bf16(a2, b0, acc[6][0], 0, 0, 0);
    acc[6][1] = __builtin_amdgcn_mfma_f32_16x16x32_bf16(a2, b1, acc[6][1], 0, 0, 0);
    acc[6][2] = __builtin_amdgcn_mfma_f32_16x16x32_bf16(a2, b2, acc[6][2], 0, 0, 0);
    acc[6][3] = __builtin_amdgcn_mfma_f32_16x16x32_bf16(a2, b3, acc[6][3], 0, 0, 0);
    acc[7][0] = __builtin_amdgcn_mfma_f32_16x16x32_bf16(a3, b0, acc[7][0], 0, 0, 0);
    acc[7][1] = __builtin_amdgcn_mfma_f32_16x16x32_bf16(a3, b1, acc[7][1], 0, 0, 0);
    acc[7][2] = __builtin_amdgcn_mfma_f32_16x16x32_bf16(a3, b2, acc[7][2], 0, 0, 0);
    acc[7][3] = __builtin_amdgcn_mfma_f32_16x16x32_bf16(a3, b3, acc[7][3], 0, 0, 0);
    __builtin_amdgcn_s_setprio(0);
    const int rem = nt - 2 - t;
    if (rem >= 2)      asm volatile("s_waitcnt vmcnt(8)" ::: "memory");
    else if (rem == 1) asm volatile("s_waitcnt vmcnt(4)" ::: "memory");
    else               asm volatile("s_waitcnt vmcnt(0)" ::: "memory");
    __builtin_amdgcn_s_barrier();
    __builtin_amdgcn_sched_barrier(0);
  }
#undef STAGE_A
#undef STAGE_B
#undef LDA
#undef LDB

#pragma unroll
  for (int m = 0; m < 8; ++m) {
    const int rb = m0 + wm * 128 + m * 16 + lg * 4;
#pragma unroll
    for (int n = 0; n < 4; ++n) {
      const int col = n0 + wn * 64 + n * 16 + lr;
      const float bv = bias[col];
#pragma unroll
      for (int r = 0; r < 4; ++r) {
        const size_t idx = (size_t)(rb + r) * N + col;
        float v = acc[m][n][r] + bv;
        if (MODE == 2) v = gelu_f(v);
        if (MODE == 3) {
          ((float*)Cout)[idx] = v + bf2f(addb[idx]) + addf[idx];
        } else {
          ((unsigned short*)Cout)[idx] = f2bf(v);
        }
      }
    }
  }
}

extern "C" void kernel_launch(void* const* d_in, const int* in_sizes, int n_in,
                              void* d_out, int out_size, void* d_ws, size_t ws_size,
                              hipStream_t stream) {
  (void)in_sizes; (void)n_in; (void)out_size; (void)ws_size;
  const float* hidden = (const float*)d_in[1];
  const float* ln_g = (const float*)d_in[2];
  const float* ln_b = (const float*)d_in[3];
  const float* wqkv = (const float*)d_in[4];
  const float* bqkv = (const float*)d_in[5];
  const float* wout = (const float*)d_in[6];
  const float* bout = (const float*)d_in[7];
  const float* wfc1 = (const float*)d_in[8];
  const float* bfc1 = (const float*)d_in[9];
  const float* wfc2 = (const float*)d_in[10];
  const float* bfc2 = (const float*)d_in[11];
  float* out = (float*)d_out;

  char* ws = (char*)d_ws;
  size_t off = 0;
  auto alloc = [&](size_t bytes) -> void* {
    void* p = ws + off;
    off += (bytes + 255) & ~(size_t)255;
    return p;
  };
  unsigned short* wqkvT = (unsigned short*)alloc((size_t)3 * DD * DD * 2);
  unsigned short* woutT = (unsigned short*)alloc((size_t)DD * DD * 2);
  unsigned short* wfc1T = (unsigned short*)alloc((size_t)NII * DD * 2);
  unsigned short* wfc2T = (unsigned short*)alloc((size_t)DD * NII * 2);
  unsigned short* xln   = (unsigned short*)alloc((size_t)NTOK * DD * 2);
  unsigned short* regA  = (unsigned short*)alloc((size_t)NTOK * NII * 2);  // qkv, then h1
  unsigned short* Qp    = (unsigned short*)alloc((size_t)2 * HH * SS * DPAD * 2);  // then attn_proj
  unsigned short* Kp    = (unsigned short*)alloc((size_t)2 * HH * SS * DPAD * 2);
  unsigned short* Vt    = (unsigned short*)alloc((size_t)2 * HH * DHH * SS * 2);
  unsigned short* Obuf  = (unsigned short*)alloc((size_t)NTOK * DD * 2);
  unsigned short* qkvbuf   = regA;
  unsigned short* h1       = regA;
  unsigned short* attnproj = Qp;

  wt_transpose<<<dim3(3 * DD / 32, DD / 32), 256, 0, stream>>>(wqkv, wqkvT, DD, 3 * DD);
  wt_transpose<<<dim3(DD / 32, DD / 32), 256, 0, stream>>>(wout, woutT, DD, DD);
  wt_transpose<<<dim3(NII / 32, DD / 32), 256, 0, stream>>>(wfc1, wfc1T, DD, NII);
  wt_transpose<<<dim3(DD / 32, NII / 32), 256, 0, stream>>>(wfc2, wfc2T, NII, DD);
  ln_kernel<<<NTOK, 256, 0, stream>>>(hidden, ln_g, ln_b, xln);
  gemm256<0><<<dim3((3 * DD / 256) * (NTOK / 256)), 512, 0, stream>>>(
      xln, wqkvT, bqkv, qkvbuf, nullptr, nullptr, NTOK, 3 * DD, DD, 3 * DD / 256);
  rope_kernel<<<NTOK, 256, 0, stream>>>(qkvbuf, Qp, Kp, Vt);
  attn_kernel<<<dim3(4096), 128, 0, stream>>>(Qp, Kp, Vt, Obuf);
  gemm256<0><<<dim3((DD / 256) * (NTOK / 256)), 512, 0, stream>>>(
      Obuf, woutT, bout, attnproj, nullptr, nullptr, NTOK, DD, DD, DD / 256);
  gemm256<2><<<dim3((NII / 256) * (NTOK / 256)), 512, 0, stream>>>(
      xln, wfc1T, bfc1, h1, nullptr, nullptr, NTOK, NII, DD, NII / 256);
  gemm256<3><<<dim3((DD / 256) * (NTOK / 256)), 512, 0, stream>>>(
      h1, wfc2T, bfc2, out, attnproj, hidden, NTOK, DD, NII, DD / 256);
}

// Round 4
// 1312.796 us; speedup vs baseline: 1.3700x; 1.0100x over previous
//
#include <hip/hip_runtime.h>

#define SS   2048
#define DD   2560
#define HH   32
#define DHH  80
#define DPAD 96
#define NII  10240
#define NTOK 4096

typedef __attribute__((ext_vector_type(8))) __bf16 bf16x8;
typedef __attribute__((ext_vector_type(4))) float  f32x4;

__device__ __forceinline__ float bf2f(unsigned short h) {
  union { unsigned u; float f; } c; c.u = ((unsigned)h) << 16; return c.f;
}
__device__ __forceinline__ unsigned short f2bf(float f) {
  union { float f; unsigned u; } c; c.f = f;
  unsigned r = c.u + 0x7FFFu + ((c.u >> 16) & 1u);
  return (unsigned short)(r >> 16);
}

__device__ __forceinline__ void gl_lds16(const void* gptr, void* lptr) {
  __builtin_amdgcn_global_load_lds((__attribute__((address_space(1))) void*)gptr,
                                   (__attribute__((address_space(3))) void*)lptr,
                                   16, 0, 0);
}

// ---------------- weight transpose: W[K][N] fp32 -> Wt[N][K] bf16 ----------------
__global__ __launch_bounds__(256) void wt_transpose(const float* __restrict__ W,
                                                    unsigned short* __restrict__ Wt,
                                                    int K, int N) {
  __shared__ float tile[32][33];
  const int tx = threadIdx.x & 31, ty = threadIdx.x >> 5;
  const int n0 = blockIdx.x * 32, k0 = blockIdx.y * 32;
#pragma unroll
  for (int i = 0; i < 32; i += 8)
    tile[ty + i][tx] = W[(size_t)(k0 + ty + i) * N + n0 + tx];
  __syncthreads();
#pragma unroll
  for (int i = 0; i < 32; i += 8)
    Wt[(size_t)(n0 + ty + i) * K + k0 + tx] = f2bf(tile[tx][ty + i]);
}

// ---------------- LayerNorm: fp32 in -> bf16 out ----------------
__global__ __launch_bounds__(256) void ln_kernel(const float* __restrict__ X,
                                                 const float* __restrict__ G,
                                                 const float* __restrict__ Bb,
                                                 unsigned short* __restrict__ Xo) {
  const int row = blockIdx.x;
  const float4* xr = (const float4*)(X + (size_t)row * DD);
  float s = 0.f, ss = 0.f;
  for (int i = threadIdx.x; i < DD / 4; i += 256) {
    float4 v = xr[i];
    s  += v.x + v.y + v.z + v.w;
    ss += v.x * v.x + v.y * v.y + v.z * v.z + v.w * v.w;
  }
#pragma unroll
  for (int o = 32; o > 0; o >>= 1) { s += __shfl_down(s, o, 64); ss += __shfl_down(ss, o, 64); }
  __shared__ float red[8];
  const int w = threadIdx.x >> 6;
  if ((threadIdx.x & 63) == 0) { red[w] = s; red[4 + w] = ss; }
  __syncthreads();
  if (threadIdx.x == 0) {
    float ts  = red[0] + red[1] + red[2] + red[3];
    float tss = red[4] + red[5] + red[6] + red[7];
    float mu  = ts * (1.f / DD);
    float var = tss * (1.f / DD) - mu * mu;
    red[0] = mu; red[1] = rsqrtf(var + 1e-5f);
  }
  __syncthreads();
  const float mu = red[0], rstd = red[1];
  const float4* gr = (const float4*)G;
  const float4* br = (const float4*)Bb;
  for (int i = threadIdx.x; i < DD / 4; i += 256) {
    float4 v = xr[i], g = gr[i], b = br[i];
    ushort4 o;
    o.x = f2bf((v.x - mu) * rstd * g.x + b.x);
    o.y = f2bf((v.y - mu) * rstd * g.y + b.y);
    o.z = f2bf((v.z - mu) * rstd * g.z + b.z);
    o.w = f2bf((v.w - mu) * rstd * g.w + b.w);
    *(ushort4*)&Xo[(size_t)row * DD + i * 4] = o;
  }
}

// ---------------- RoPE + head-layout ----------------
__global__ __launch_bounds__(256) void rope_kernel(const unsigned short* __restrict__ qkv,
                                                   unsigned short* __restrict__ Qp,
                                                   unsigned short* __restrict__ Kp,
                                                   unsigned short* __restrict__ Vt) {
  const int tok = blockIdx.x;
  const int b = tok / SS, s = tok % SS;
  __shared__ float cs[16], sn[16];
  if (threadIdx.x < 16) {
    float inv = powf(10000.f, -(float)threadIdx.x / 16.f);
    float ang = (float)s * inv;
    cs[threadIdx.x] = cosf(ang);
    sn[threadIdx.x] = sinf(ang);
  }
  __syncthreads();
  const unsigned short* row = qkv + (size_t)tok * (3 * DD);
  for (int idx = threadIdx.x; idx < 2 * HH * DPAD; idx += 256) {
    const int which = idx / (HH * DPAD);
    const int rrem  = idx % (HH * DPAD);
    const int h = rrem / DPAD, d = rrem % DPAD;
    float val = 0.f;
    if (d < DHH) {
      const unsigned short* base = row + which * DD + h * DHH;
      if (d < 16) {
        float x1 = bf2f(base[d]), x2 = bf2f(base[d + 16]);
        val = x1 * cs[d] - x2 * sn[d];
      } else if (d < 32) {
        int i2 = d - 16;
        float x1 = bf2f(base[i2]), x2 = bf2f(base[d]);
        val = x2 * cs[i2] + x1 * sn[i2];
      } else {
        val = bf2f(base[d]);
      }
    }
    unsigned short* outp = which ? Kp : Qp;
    outp[(((size_t)b * HH + h) * SS + s) * DPAD + d] = f2bf(val);
  }
  for (int idx = threadIdx.x; idx < DD; idx += 256) {
    const int h = idx / DHH, d = idx % DHH;
    Vt[(((size_t)b * HH + h) * DHH + d) * SS + s] = row[2 * DD + idx];
  }
}

// ---------------- flash attention (causal), 2-wave blocks, 16 q-rows/wave, KVBLK=64 ----------------
__global__ __launch_bounds__(128) void attn_kernel(const unsigned short* __restrict__ Qp,
                                                   const unsigned short* __restrict__ Kp,
                                                   const unsigned short* __restrict__ Vt,
                                                   unsigned short* __restrict__ O) {
  const int bid = blockIdx.x;
  const int bh = bid & 63;
  const int p = 63 - (bid >> 6);        // heavy first
  const int w = threadIdx.x >> 6;
  const int tile = p * 2 + w;
  const int lane = threadIdx.x & 63;
  const int lr = lane & 15, lg = lane >> 4;
  const int q0 = tile * 16;
  const unsigned short* Qh = Qp + (size_t)bh * SS * DPAD;
  const unsigned short* Kh = Kp + (size_t)bh * SS * DPAD;
  const unsigned short* Vh = Vt + (size_t)bh * DHH * SS;
  __shared__ __align__(16) char Plds[2][2048];
  char* Pb = Plds[w];

  bf16x8 qf[3];
#pragma unroll
  for (int c = 0; c < 3; ++c)
    qf[c] = *(const bf16x8*)&Qh[(size_t)(q0 + lr) * DPAD + c * 32 + lg * 8];

  f32x4 oacc[5];
#pragma unroll
  for (int d = 0; d < 5; ++d) oacc[d] = (f32x4){0.f, 0.f, 0.f, 0.f};
  float mrow[4], lrow[4];
#pragma unroll
  for (int r = 0; r < 4; ++r) { mrow[r] = -1e30f; lrow[r] = 0.f; }

  const float scl = 0.11180339887498949f;
  const int nt = q0 / 64 + 1;
  for (int t = 0; t < nt; ++t) {
    const int kv0 = t * 64;
    f32x4 s0 = (f32x4){0.f, 0.f, 0.f, 0.f};
    f32x4 s1 = (f32x4){0.f, 0.f, 0.f, 0.f};
    f32x4 s2 = (f32x4){0.f, 0.f, 0.f, 0.f};
    f32x4 s3 = (f32x4){0.f, 0.f, 0.f, 0.f};
#pragma unroll
    for (int c = 0; c < 3; ++c) {
      bf16x8 k0 = *(const bf16x8*)&Kh[(size_t)(kv0 +      lr) * DPAD + c * 32 + lg * 8];
      bf16x8 k1 = *(const bf16x8*)&Kh[(size_t)(kv0 + 16 + lr) * DPAD + c * 32 + lg * 8];
      bf16x8 k2 = *(const bf16x8*)&Kh[(size_t)(kv0 + 32 + lr) * DPAD + c * 32 + lg * 8];
      bf16x8 k3 = *(const bf16x8*)&Kh[(size_t)(kv0 + 48 + lr) * DPAD + c * 32 + lg * 8];
      s0 = __builtin_amdgcn_mfma_f32_16x16x32_bf16(qf[c], k0, s0, 0, 0, 0);
      s1 = __builtin_amdgcn_mfma_f32_16x16x32_bf16(qf[c], k1, s1, 0, 0, 0);
      s2 = __builtin_amdgcn_mfma_f32_16x16x32_bf16(qf[c], k2, s2, 0, 0, 0);
      s3 = __builtin_amdgcn_mfma_f32_16x16x32_bf16(qf[c], k3, s3, 0, 0, 0);
    }
    float pv0[4], pv1[4], pv2[4], pv3[4], mx[4];
    bool need = false;
#pragma unroll
    for (int r = 0; r < 4; ++r) {
      const int qr = q0 + lg * 4 + r;
      float a0 = (kv0 +      lr > qr) ? -1e30f : s0[r] * scl;
      float a1 = (kv0 + 16 + lr > qr) ? -1e30f : s1[r] * scl;
      float a2 = (kv0 + 32 + lr > qr) ? -1e30f : s2[r] * scl;
      float a3 = (kv0 + 48 + lr > qr) ? -1e30f : s3[r] * scl;
      pv0[r] = a0; pv1[r] = a1; pv2[r] = a2; pv3[r] = a3;
      float m = fmaxf(fmaxf(a0, a1), fmaxf(a2, a3));
#pragma unroll
      for (int mk = 1; mk < 16; mk <<= 1) m = fmaxf(m, __shfl_xor(m, mk, 64));
      mx[r] = m;
      need = need || (m > mrow[r] + 8.f);
    }
    if (__ballot(need)) {
#pragma unroll
      for (int r = 0; r < 4; ++r) {
        float mnew = fmaxf(mrow[r], mx[r]);
        float resc = __expf(mrow[r] - mnew);
        lrow[r] *= resc;
#pragma unroll
        for (int d = 0; d < 5; ++d) oacc[d][r] *= resc;
        mrow[r] = mnew;
      }
    }
#pragma unroll
    for (int r = 0; r < 4; ++r) {
      const int row = lg * 4 + r;
      const int swz = (row & 7) << 4;
      float p0 = __expf(pv0[r] - mrow[r]);
      float p1 = __expf(pv1[r] - mrow[r]);
      float p2 = __expf(pv2[r] - mrow[r]);
      float p3 = __expf(pv3[r] - mrow[r]);
      *(unsigned short*)(Pb + row * 128 + ((( 0 + lr) * 2) ^ swz)) = f2bf(p0);
      *(unsigned short*)(Pb + row * 128 + (((16 + lr) * 2) ^ swz)) = f2bf(p1);
      *(unsigned short*)(Pb + row * 128 + (((32 + lr) * 2) ^ swz)) = f2bf(p2);
      *(unsigned short*)(Pb + row * 128 + (((48 + lr) * 2) ^ swz)) = f2bf(p3);
      float rs = (p0 + p1) + (p2 + p3);
#pragma unroll
      for (int mk = 1; mk < 16; mk <<= 1) rs += __shfl_xor(rs, mk, 64);
      lrow[r] += rs;
    }
    asm volatile("s_waitcnt lgkmcnt(0)" ::: "memory");
    const int rswz = (lr & 7) << 4;
    bf16x8 pa0 = *(const bf16x8*)(Pb + lr * 128 + ((lg * 16) ^ rswz));
    bf16x8 pa1 = *(const bf16x8*)(Pb + lr * 128 + ((64 + lg * 16) ^ rswz));
#pragma unroll
    for (int d = 0; d < 5; ++d) {
      bf16x8 v0 = *(const bf16x8*)&Vh[(size_t)(d * 16 + lr) * SS + kv0 + lg * 8];
      bf16x8 v1 = *(const bf16x8*)&Vh[(size_t)(d * 16 + lr) * SS + kv0 + 32 + lg * 8];
      oacc[d] = __builtin_amdgcn_mfma_f32_16x16x32_bf16(pa0, v0, oacc[d], 0, 0, 0);
      oacc[d] = __builtin_amdgcn_mfma_f32_16x16x32_bf16(pa1, v1, oacc[d], 0, 0, 0);
    }
  }
  const int b = bh >> 5, h = bh & 31;
#pragma unroll
  for (int r = 0; r < 4; ++r) {
    const int qr = q0 + lg * 4 + r;
    const float inv = 1.f / lrow[r];
#pragma unroll
    for (int d = 0; d < 5; ++d)
      O[(size_t)(b * SS + qr) * DD + h * DHH + d * 16 + lr] = f2bf(oacc[d][r] * inv);
  }
}

// ---------------- 256x256 GEMM, 8 waves, m201-style 4-phase/K-tile(64) pipeline ----------------
__device__ __forceinline__ float gelu_f(float x) {
  float x3 = x * x * x;
  return 0.5f * x * (1.f + tanhf(0.7978845608028654f * (x + 0.044715f * x3)));
}

// LDS map (128 KB): A: [buf][khalf][256 rows][32 k] bf16 at buf*32768 + khalf*16384
//                   B: same at +65536.
// MODE 0: out bf16 = C + bias ; MODE 2: bf16 gelu(C+bias) ; MODE 3: fp32 C+bias+bf16(addb)+addf
template <int MODE>
__global__ __launch_bounds__(512, 2) void gemm256(const unsigned short* __restrict__ A,
                                                  const unsigned short* __restrict__ Bt,
                                                  const float* __restrict__ bias,
                                                  void* __restrict__ Cout,
                                                  const unsigned short* __restrict__ addb,
                                                  const float* __restrict__ addf,
                                                  int M, int N, int K, int nbx) {
  __shared__ __align__(16) char lds[131072];

  // bijective XCD swizzle (m204)
  const int nwg = gridDim.x;
  const int orig = blockIdx.x;
  const int qq = nwg >> 3, rr = nwg & 7;
  const int xcd = orig & 7, loc = orig >> 3;
  const int swz = (xcd < rr ? xcd * (qq + 1) : rr * (qq + 1) + (xcd - rr) * qq) + loc;
  const int by = swz / nbx, bx = swz % nbx;
  const int m0 = by * 256, n0 = bx * 256;

  const int tid = threadIdx.x;
  const int w = tid >> 6, lane = tid & 63;
  const int lr = lane & 15, lg = lane >> 4;
  const int wm = w & 1, wn = w >> 1;

  // staging: half-tile = [256 rows][32 k]; wave w covers rows w*32..w*32+31 (2 issues).
  // linear LDS dest; source k-slot pre-swizzled: kc = ((l&3) ^ ((l>>3)&3))*8
  const int srow = w * 32 + (lane >> 2);
  const int skc  = ((lane & 3) ^ ((lane >> 3) & 3)) * 8;
  const unsigned short* aSrc = A  + (size_t)(m0 + srow) * K + skc;
  const unsigned short* bSrc = Bt + (size_t)(n0 + srow) * K + skc;
  const int sdst = w * 2048;

  // fragment read: row stride 64B, swizzled 16B slot = lg ^ ((lr>>1)&3)
  const int fsw = (lg ^ ((lr >> 1) & 3)) << 4;
  const int arowb = (wm * 128 + lr) * 64;  // + m*1024
  const int browb = (wn * 64 + lr) * 64;   // + n*1024

  f32x4 acc[8][4];
#pragma unroll
  for (int i = 0; i < 8; ++i)
#pragma unroll
    for (int j = 0; j < 4; ++j) acc[i][j] = (f32x4){0.f, 0.f, 0.f, 0.f};

  const int nt = K >> 6;  // K-tiles of 64

#define STG(srcp, kt, h, base)                                          \
  { const unsigned short* _g = (srcp) + (size_t)(kt) * 64 + (h) * 32;   \
    gl_lds16(_g, lds + (base) + sdst);                                  \
    gl_lds16(_g + (size_t)16 * K, lds + (base) + sdst + 1024); }
#define LDAF(base, h, m) (*(const bf16x8*)(lds + (base) + (h) * 16384 + arowb + (m) * 1024 + fsw))
#define LDBF(base, h, n) (*(const bf16x8*)(lds + (base) + (h) * 16384 + browb + (n) * 1024 + fsw))
#define MFMA16(lo)                                                      \
  _Pragma("unroll") for (int i = 0; i < 4; ++i)                         \
  _Pragma("unroll") for (int j = 0; j < 4; ++j)                         \
    acc[(lo) + i][j] = __builtin_amdgcn_mfma_f32_16x16x32_bf16(av[i], bv[j], acc[(lo) + i][j], 0, 0, 0);

  // prologue: tile0 all 4 halves + tile1 k0 halves; invariant: 2 halves (4 loads) in flight
  STG(aSrc, 0, 0, 0);
  STG(bSrc, 0, 0, 65536);
  STG(aSrc, 0, 1, 16384);
  STG(bSrc, 0, 1, 65536 + 16384);
  STG(aSrc, 1, 0, 32768);
  STG(bSrc, 1, 0, 65536 + 32768);
  asm volatile("s_waitcnt vmcnt(4)" ::: "memory");
  __builtin_amdgcn_s_barrier();
  __builtin_amdgcn_sched_barrier(0);

  for (int k = 0; k < nt; ++k) {
    const int c = k & 1;
    const int cAb = c * 32768,         cBb = 65536 + c * 32768;
    const int nAb = (c ^ 1) * 32768,   nBb = 65536 + (c ^ 1) * 32768;
    bf16x8 av[4], bv[4];
    // ---- P1: k0 x m0-3 ----
#pragma unroll
    for (int i = 0; i < 4; ++i) av[i] = LDAF(cAb, 0, i);
#pragma unroll
    for (int j = 0; j < 4; ++j) bv[j] = LDBF(cBb, 0, j);
    if (k + 1 < nt) STG(aSrc, k + 1, 1, nAb + 16384);
    __builtin_amdgcn_s_barrier();
    __builtin_amdgcn_s_setprio(1);
    MFMA16(0);
    __builtin_amdgcn_s_setprio(0);
    __builtin_amdgcn_s_barrier();
    // ---- P2: k0 x m4-7 ----
#pragma unroll
    for (int i = 0; i < 4; ++i) av[i] = LDAF(cAb, 0, 4 + i);
    if (k + 1 < nt) STG(bSrc, k + 1, 1, nBb + 16384);
    __builtin_amdgcn_s_barrier();
    __builtin_amdgcn_s_setprio(1);
    MFMA16(4);
    __builtin_amdgcn_s_setprio(0);
    __builtin_amdgcn_s_barrier();
    // ---- P3: k1 x m0-3 ----
#pragma unroll
    for (int i = 0; i < 4; ++i) av[i] = LDAF(cAb, 1, i);
#pragma unroll
    for (int j = 0; j < 4; ++j) bv[j] = LDBF(cBb, 1, j);
    if (k + 2 < nt) STG(aSrc, k + 2, 0, cAb);
    __builtin_amdgcn_s_barrier();
    __builtin_amdgcn_s_setprio(1);
    MFMA16(0);
    __builtin_amdgcn_s_setprio(0);
    __builtin_amdgcn_s_barrier();
    // ---- P4: k1 x m4-7 ----
#pragma unroll
    for (int i = 0; i < 4; ++i) av[i] = LDAF(cAb, 1, 4 + i);
    if (k + 2 < nt) STG(bSrc, k + 2, 0, cBb);
    __builtin_amdgcn_s_barrier();
    __builtin_amdgcn_s_setprio(1);
    MFMA16(4);
    __builtin_amdgcn_s_setprio(0);
    // ---- tile boundary: counted vmcnt (4 halves needed resident; 2 may fly) ----
    const int rem = nt - 1 - k;
    if (rem >= 2) asm volatile("s_waitcnt vmcnt(4)" ::: "memory");
    else          asm volatile("s_waitcnt vmcnt(0)" ::: "memory");
    __builtin_amdgcn_s_barrier();
    __builtin_amdgcn_sched_barrier(0);
  }
#undef STG
#undef LDAF
#undef LDBF
#undef MFMA16

  // epilogue
#pragma unroll
  for (int m = 0; m < 8; ++m) {
    const int rb = m0 + wm * 128 + m * 16 + lg * 4;
#pragma unroll
    for (int n = 0; n < 4; ++n) {
      const int col = n0 + wn * 64 + n * 16 + lr;
      const float bv = bias[col];
#pragma unroll
      for (int r = 0; r < 4; ++r) {
        const size_t idx = (size_t)(rb + r) * N + col;
        float v = acc[m][n][r] + bv;
        if (MODE == 2) v = gelu_f(v);
        if (MODE == 3) {
          ((float*)Cout)[idx] = v + bf2f(addb[idx]) + addf[idx];
        } else {
          ((unsigned short*)Cout)[idx] = f2bf(v);
        }
      }
    }
  }
}

extern "C" void kernel_launch(void* const* d_in, const int* in_sizes, int n_in,
                              void* d_out, int out_size, void* d_ws, size_t ws_size,
                              hipStream_t stream) {
  (void)in_sizes; (void)n_in; (void)out_size; (void)ws_size;
  const float* hidden = (const float*)d_in[1];
  const float* ln_g = (const float*)d_in[2];
  const float* ln_b = (const float*)d_in[3];
  const float* wqkv = (const float*)d_in[4];
  const float* bqkv = (const float*)d_in[5];
  const float* wout = (const float*)d_in[6];
  const float* bout = (const float*)d_in[7];
  const float* wfc1 = (const float*)d_in[8];
  const float* bfc1 = (const float*)d_in[9];
  const float* wfc2 = (const float*)d_in[10];
  const float* bfc2 = (const float*)d_in[11];
  float* out = (float*)d_out;

  char* ws = (char*)d_ws;
  size_t off = 0;
  auto alloc = [&](size_t bytes) -> void* {
    void* p = ws + off;
    off += (bytes + 255) & ~(size_t)255;
    return p;
  };
  unsigned short* wqkvT = (unsigned short*)alloc((size_t)3 * DD * DD * 2);
  unsigned short* woutT = (unsigned short*)alloc((size_t)DD * DD * 2);
  unsigned short* wfc1T = (unsigned short*)alloc((size_t)NII * DD * 2);
  unsigned short* wfc2T = (unsigned short*)alloc((size_t)DD * NII * 2);
  unsigned short* xln   = (unsigned short*)alloc((size_t)NTOK * DD * 2);
  unsigned short* regA  = (unsigned short*)alloc((size_t)NTOK * NII * 2);  // qkv, then h1
  unsigned short* Qp    = (unsigned short*)alloc((size_t)2 * HH * SS * DPAD * 2);  // then attn_proj
  unsigned short* Kp    = (unsigned short*)alloc((size_t)2 * HH * SS * DPAD * 2);
  unsigned short* Vt    = (unsigned short*)alloc((size_t)2 * HH * DHH * SS * 2);
  unsigned short* Obuf  = (unsigned short*)alloc((size_t)NTOK * DD * 2);
  unsigned short* qkvbuf   = regA;
  unsigned short* h1       = regA;
  unsigned short* attnproj = Qp;

  wt_transpose<<<dim3(3 * DD / 32, DD / 32), 256, 0, stream>>>(wqkv, wqkvT, DD, 3 * DD);
  wt_transpose<<<dim3(DD / 32, DD / 32), 256, 0, stream>>>(wout, woutT, DD, DD);
  wt_transpose<<<dim3(NII / 32, DD / 32), 256, 0, stream>>>(wfc1, wfc1T, DD, NII);
  wt_transpose<<<dim3(DD / 32, NII / 32), 256, 0, stream>>>(wfc2, wfc2T, NII, DD);
  ln_kernel<<<NTOK, 256, 0, stream>>>(hidden, ln_g, ln_b, xln);
  gemm256<0><<<dim3((3 * DD / 256) * (NTOK / 256)), 512, 0, stream>>>(
      xln, wqkvT, bqkv, qkvbuf, nullptr, nullptr, NTOK, 3 * DD, DD, 3 * DD / 256);
  rope_kernel<<<NTOK, 256, 0, stream>>>(qkvbuf, Qp, Kp, Vt);
  attn_kernel<<<dim3(4096), 128, 0, stream>>>(Qp, Kp, Vt, Obuf);
  gemm256<0><<<dim3((DD / 256) * (NTOK / 256)), 512, 0, stream>>>(
      Obuf, woutT, bout, attnproj, nullptr, nullptr, NTOK, DD, DD, DD / 256);
  gemm256<2><<<dim3((NII / 256) * (NTOK / 256)), 512, 0, stream>>>(
      xln, wfc1T, bfc1, h1, nullptr, nullptr, NTOK, NII, DD, NII / 256);
  gemm256<3><<<dim3((DD / 256) * (NTOK / 256)), 512, 0, stream>>>(
      h1, wfc2T, bfc2, out, attnproj, hidden, NTOK, DD, NII, DD / 256);
}